// Round 15
// baseline (1823.916 us; speedup 1.0000x reference)
//
#include <hip/hip_runtime.h>
#include <hip/hip_bf16.h>

// 2-layer LSTM (T=1024, B=512, IN=20, H1=128, H2=64) + head OUT=3.
// Only batch row 511 feeds the output => single-sequence scan.
//
// Pipeline:
//   A : xp1 = x[:,511,:] @ W_ih0^T + b0            (parallel)
//   P : pack W_hh0/W_hh1 f16 to coalesced global   (parallel, once)
//   B1: layer-1 scan — W in VGPRs, 1 wave/SIMD     (serial, 1 CU)
//   C1: xp2 = h1seq @ W_ih1^T + b1                 (parallel GEMM)
//   B2: layer-2 scan — same                         (serial, 1 CU)
//   D : head                                        (parallel)
//
// Round-15: R7/R12/R13/R14 all floor at ~2300-2500 cyc/step with totally
// different LDS loads -> the invariant is the per-step W stream (128-256KB
// re-read from L2 after each barrier; ~60B/cyc/CU => ~2000 cyc exposed).
// Fix: 256 threads = 1 wave/SIMD = 512-VGPR budget (the one occupancy tier
// where the allocator has real headroom). Thread owns 2 FULL gate rows as
// 32 packed-f16 u4 (128 VGPRs), loaded once + asm-pinned. No partials.
// Numerics unchanged: f16 W, exact hi/lo-f16 h (lo x4096).

#define T_STEPS 1024
#define BATCH   512
#define IN_F    20
#define H1_     128
#define H2_     64
#define OUT_F   3
#define G1_     (4*H1_)   // 512
#define G2_     (4*H2_)   // 256

typedef float f4 __attribute__((ext_vector_type(4)));
typedef float f2 __attribute__((ext_vector_type(2)));
typedef unsigned int u32;
typedef u32 u4 __attribute__((ext_vector_type(4)));
typedef _Float16 h2t __attribute__((ext_vector_type(2)));

__device__ __forceinline__ float sigmoidf_(float x) {
    return 1.0f / (1.0f + __expf(-x));
}
__device__ __forceinline__ float tanhf_(float x) {
    return 1.0f - 2.0f / (__expf(2.0f * x) + 1.0f);
}
__device__ __forceinline__ h2t as_h2(u32 v) {
    union { u32 u; h2t h; } c; c.u = v; return c.h;
}
__device__ __forceinline__ u32 pkh(float a, float b) {
    union { _Float16 h[2]; u32 u; } c;
    c.h[0] = (_Float16)a; c.h[1] = (_Float16)b; return c.u;
}
__device__ __forceinline__ float fdot2_(h2t a, h2t b, float c) {
#if __has_builtin(__builtin_amdgcn_fdot2)
    return __builtin_amdgcn_fdot2(a, b, c, false);
#else
    float d = c;
    asm("v_dot2_f32_f16 %0, %1, %2, %0" : "+v"(d) : "v"(a), "v"(b));
    return d;
#endif
}
__device__ __forceinline__ u4 packq(const float* p) {
    const f4 a = *(const f4*)p;
    const f4 b = *(const f4*)(p + 4);
    u4 pk;
    pk.x = pkh(a.x, a.y); pk.y = pkh(a.z, a.w);
    pk.z = pkh(b.x, b.y); pk.w = pkh(b.z, b.w);
    return pk;
}

#define LO_SCALE_INV 0.000244140625f   // 2^-12

#define REPQ8(M)  M(0) M(1) M(2) M(3) M(4) M(5) M(6) M(7)
#define REPQ16(M) REPQ8(M) M(8) M(9) M(10) M(11) M(12) M(13) M(14) M(15)

// 8 fdot2 against one W quad into named accums (hi: A0/A1, lo: A2/A3)
#define DOTQ4(WQ, HH, HL, A0, A1, A2, A3)                                     \
    { A0 = fdot2_(as_h2((WQ).x), as_h2((HH).x), A0);                          \
      A1 = fdot2_(as_h2((WQ).y), as_h2((HH).y), A1);                          \
      A0 = fdot2_(as_h2((WQ).z), as_h2((HH).z), A0);                          \
      A1 = fdot2_(as_h2((WQ).w), as_h2((HH).w), A1);                          \
      A2 = fdot2_(as_h2((WQ).x), as_h2((HL).x), A2);                          \
      A3 = fdot2_(as_h2((WQ).y), as_h2((HL).y), A3);                          \
      A2 = fdot2_(as_h2((WQ).z), as_h2((HL).z), A2);                          \
      A3 = fdot2_(as_h2((WQ).w), as_h2((HL).w), A3); }

// ---------------- A: x-projection for batch row 511 --------------------------
__global__ void xproj_kernel(const float* __restrict__ x,
                             const float* __restrict__ W_ih0,
                             const float* __restrict__ b_ih0,
                             const float* __restrict__ b_hh0,
                             float* __restrict__ xp1)
{
    const int t = blockIdx.x;
    const int g = threadIdx.x;
    const float* xr = x + ((size_t)t * BATCH + (BATCH - 1)) * IN_F;
    const float* w  = W_ih0 + g * IN_F;
    float acc = b_ih0[g] + b_hh0[g];
#pragma unroll
    for (int i = 0; i < IN_F; ++i) acc = fmaf(xr[i], w[i], acc);
    xp1[t * G1_ + g] = acc;
}

// ---------------- P: pack W f16, coalesced for the register load -------------
// wpk1[q*256 + r], q in [0,32), r in [0,256):
//   gate g = 2r + (q>>4), cols (q&15)*8 .. +8   (128 KB)
// wpk2[q*256 + r], q in [0,8): = W_hh1[r][q*8 .. +8)   (32 KB)
__global__ void pack_kernel(const float* __restrict__ W_hh0,
                            const float* __restrict__ W_hh1,
                            u4* __restrict__ wpk1,
                            u4* __restrict__ wpk2)
{
    const int idx = blockIdx.x * blockDim.x + threadIdx.x;
    if (idx < 8192) {
        const int q = idx >> 8, r = idx & 255;
        const int g = 2 * r + (q >> 4);
        wpk1[idx] = packq(W_hh0 + (size_t)g * H1_ + (q & 15) * 8);
    } else if (idx < 8192 + 2048) {
        const int i2 = idx - 8192;
        const int q = i2 >> 8, r = i2 & 255;
        wpk2[i2] = packq(W_hh1 + (size_t)r * H2_ + q * 8);
    }
}

// ---------------- B1: layer-1 scan (serial, one block) -----------------------
// 256 thr = 4 waves = 1 wave/SIMD -> 512-VGPR budget. Thread tid owns gates
// {2tid, 2tid+1} fully: 32 packed-f16 W quads (128 VGPRs), loaded once and
// asm-pinned. Per step: 32 LDS h-broadcasts + 256 fdot2, one ds_write_b64
// of both complete gates, 2 barriers. NO per-step W traffic.
__global__ __attribute__((amdgpu_flat_work_group_size(256, 256),
                          amdgpu_waves_per_eu(1, 1)))
void lstm1_kernel(const float* __restrict__ xp1,
                  const u4* __restrict__ wpk1,
                  float* __restrict__ h1seq)
{
    const int tid = threadIdx.x;

    __shared__ u4    shhi[16];         // h_hi  f16[128]
    __shared__ u4    shlo[16];         // h_lo*4096 f16[128]
    __shared__ float sg[G1_];          // complete gate pre-activations (2 KB)

    // ---- load W once into 32 named register quads (coalesced) --------------
#define LWA(k) u4 wA##k = wpk1[(k) * 256 + tid];
    REPQ16(LWA)
#undef LWA
#define LWB(k) u4 wB##k = wpk1[((k) + 16) * 256 + tid];
    REPQ16(LWB)
#undef LWB
    // opaque pin: values "may be modified" -> rematerializing the loads
    // inside the loop is illegal; at ~300/512 VGPR demand nothing spills.
    asm volatile("" : "+v"(wA0), "+v"(wA1), "+v"(wA2), "+v"(wA3),
                      "+v"(wA4), "+v"(wA5), "+v"(wA6), "+v"(wA7),
                      "+v"(wA8), "+v"(wA9), "+v"(wA10), "+v"(wA11),
                      "+v"(wA12), "+v"(wA13), "+v"(wA14), "+v"(wA15));
    asm volatile("" : "+v"(wB0), "+v"(wB1), "+v"(wB2), "+v"(wB3),
                      "+v"(wB4), "+v"(wB5), "+v"(wB6), "+v"(wB7),
                      "+v"(wB8), "+v"(wB9), "+v"(wB10), "+v"(wB11),
                      "+v"(wB12), "+v"(wB13), "+v"(wB14), "+v"(wB15));

    if (tid < 16) { shhi[tid] = u4{0,0,0,0}; shlo[tid] = u4{0,0,0,0}; }
    float c1 = 0.0f;                   // owned by tid < 128
    __syncthreads();

    f2 xpv = *(const f2*)(xp1 + 2 * tid);

    for (int t = 0; t < T_STEPS; ++t) {
        f2 xpn;
        {
            const int tn = (t + 1 < T_STEPS) ? (t + 1) : (T_STEPS - 1);
            xpn = *(const f2*)(xp1 + (size_t)tn * G1_ + 2 * tid);
        }
        // ---- h broadcast reads (wave-uniform addresses) --------------------
#define LH(k) const u4 hh##k = shhi[k]; const u4 hl##k = shlo[k];
        REPQ16(LH)
#undef LH

        float a0 = 0.f, a1 = 0.f, a2 = 0.f, a3 = 0.f;   // gate 2tid
        float b0 = 0.f, b1 = 0.f, b2 = 0.f, b3 = 0.f;   // gate 2tid+1
#define DA(k) DOTQ4(wA##k, hh##k, hl##k, a0, a1, a2, a3)
        REPQ16(DA)
#undef DA
#define DB(k) DOTQ4(wB##k, hh##k, hl##k, b0, b1, b2, b3)
        REPQ16(DB)
#undef DB

        f2 gv;
        gv.x = ((a0 + a1) + LO_SCALE_INV * (a2 + a3)) + xpv.x;
        gv.y = ((b0 + b1) + LO_SCALE_INV * (b2 + b3)) + xpv.y;
        *(f2*)(sg + 2 * tid) = gv;     // both complete gates, one b64 write
        __syncthreads();   // gates ready (also orders prev h stores)

        // ---- pointwise (tid<128): activate, update c, publish h ------------
        if (tid < H1_) {
            const float vi = sg[tid];
            const float vf = sg[H1_ + tid];
            const float vg = sg[2 * H1_ + tid];
            const float vo = sg[3 * H1_ + tid];
            c1 = fmaf(sigmoidf_(vf), c1, sigmoidf_(vi) * tanhf_(vg));
            const float h = sigmoidf_(vo) * tanhf_(c1);
            const _Float16 hh16 = (_Float16)h;
            const float hrem = (h - (float)hh16) * 4096.0f;
            ((_Float16*)shhi)[tid] = hh16;
            ((_Float16*)shlo)[tid] = (_Float16)hrem;
            h1seq[(size_t)t * H1_ + tid] = h;   // fire-and-forget (f32 state)
        }
        __syncthreads();   // h f16 arrays ready
        xpv = xpn;
    }
}

// ---------------- C1: xp2 = h1seq @ W_ih1^T + (b_ih1 + b_hh1) ---------------
__global__ void xproj2_kernel(const float* __restrict__ h1seq,
                              const float* __restrict__ W_ih1,
                              const float* __restrict__ b_ih1,
                              const float* __restrict__ b_hh1,
                              float* __restrict__ xp2)
{
    const int t = blockIdx.x;
    const int g = threadIdx.x;
    __shared__ f4 sh[H1_ / 4];
    if (g < H1_ / 4) sh[g] = ((const f4*)(h1seq + (size_t)t * H1_))[g];
    __syncthreads();
    const f4* w = (const f4*)(W_ih1 + (size_t)g * H1_);
    float ax = 0.f, ay = 0.f, az = 0.f, aw = 0.f;
#pragma unroll
    for (int k = 0; k < H1_ / 4; ++k) {
        const f4 h4 = sh[k]; const f4 w4 = w[k];
        ax = fmaf(w4.x, h4.x, ax); ay = fmaf(w4.y, h4.y, ay);
        az = fmaf(w4.z, h4.z, az); aw = fmaf(w4.w, h4.w, aw);
    }
    xp2[(size_t)t * G2_ + g] = ((ax + ay) + (az + aw)) + b_ih1[g] + b_hh1[g];
}

// ---------------- B2: layer-2 scan (serial, one block) -----------------------
// 256 thr = 4 waves = 1 wave/SIMD. Thread tid owns gate tid fully: 8 W quads
// (32 VGPRs) loaded once + pinned. 16 LDS h-broadcasts + 64 fdot2/step.
__global__ __attribute__((amdgpu_flat_work_group_size(256, 256),
                          amdgpu_waves_per_eu(1, 1)))
void lstm2_kernel(const float* __restrict__ xp2,
                  const u4* __restrict__ wpk2,
                  float* __restrict__ h2seq)
{
    const int tid = threadIdx.x;

    __shared__ u4    shhi[8];          // h_hi  f16[64]
    __shared__ u4    shlo[8];          // h_lo*4096 f16[64]
    __shared__ float sg2[G2_];         // complete gate pre-activations

#define LW2(k) u4 w##k = wpk2[(k) * 256 + tid];
    REPQ8(LW2)
#undef LW2
    asm volatile("" : "+v"(w0), "+v"(w1), "+v"(w2), "+v"(w3),
                      "+v"(w4), "+v"(w5), "+v"(w6), "+v"(w7));

    if (tid < 8) { shhi[tid] = u4{0,0,0,0}; shlo[tid] = u4{0,0,0,0}; }
    float c2 = 0.0f;                   // owned by tid < 64
    __syncthreads();

    float xp_cur = xp2[tid];

    for (int t = 0; t < T_STEPS; ++t) {
        float xp_next;
        {
            const int tn = (t + 1 < T_STEPS) ? (t + 1) : (T_STEPS - 1);
            xp_next = xp2[(size_t)tn * G2_ + tid];
        }
#define LH2(k) const u4 hh##k = shhi[k]; const u4 hl##k = shlo[k];
        REPQ8(LH2)
#undef LH2

        float a0 = 0.f, a1 = 0.f, a2 = 0.f, a3 = 0.f;
#define D2(k) DOTQ4(w##k, hh##k, hl##k, a0, a1, a2, a3)
        REPQ8(D2)
#undef D2

        sg2[tid] = ((a0 + a1) + LO_SCALE_INV * (a2 + a3)) + xp_cur;
        __syncthreads();   // gates ready (also orders prev h stores)

        if (tid < H2_) {
            const float vi = sg2[tid];
            const float vf = sg2[H2_ + tid];
            const float vg = sg2[2 * H2_ + tid];
            const float vo = sg2[3 * H2_ + tid];
            c2 = fmaf(sigmoidf_(vf), c2, sigmoidf_(vi) * tanhf_(vg));
            const float h = sigmoidf_(vo) * tanhf_(c2);
            const _Float16 hh16 = (_Float16)h;
            const float hrem = (h - (float)hh16) * 4096.0f;
            ((_Float16*)shhi)[tid] = hh16;
            ((_Float16*)shlo)[tid] = (_Float16)hrem;
            h2seq[(size_t)t * H2_ + tid] = h;
        }
        __syncthreads();   // h f16 arrays ready
        xp_cur = xp_next;
    }
}

// ---------------- D: head out[t,o] = relu(h2[t]) . W_d[o] + b_d --------------
__global__ void head_kernel(const float* __restrict__ h2seq,
                            const float* __restrict__ W_d,
                            const float* __restrict__ b_d,
                            float* __restrict__ out)
{
    const int idx = blockIdx.x * blockDim.x + threadIdx.x;
    if (idx >= T_STEPS * OUT_F) return;
    const int t = idx / OUT_F;
    const int o = idx - t * OUT_F;
    const float* hr = h2seq + (size_t)t * H2_;
    const float* w  = W_d + o * H2_;
    float acc = b_d[o];
#pragma unroll
    for (int j = 0; j < H2_; ++j) acc = fmaf(fmaxf(hr[j], 0.0f), w[j], acc);
    out[idx] = acc;
}

extern "C" void kernel_launch(void* const* d_in, const int* in_sizes, int n_in,
                              void* d_out, int out_size, void* d_ws, size_t ws_size,
                              hipStream_t stream) {
    const float* x     = (const float*)d_in[0];
    const float* W_ih0 = (const float*)d_in[1];
    const float* W_hh0 = (const float*)d_in[2];
    const float* b_ih0 = (const float*)d_in[3];
    const float* b_hh0 = (const float*)d_in[4];
    const float* W_ih1 = (const float*)d_in[5];
    const float* W_hh1 = (const float*)d_in[6];
    const float* b_ih1 = (const float*)d_in[7];
    const float* b_hh1 = (const float*)d_in[8];
    const float* W_d   = (const float*)d_in[9];
    const float* b_d   = (const float*)d_in[10];

    float* out   = (float*)d_out;
    float* xp1   = (float*)d_ws;                         // [1024][512] = 2 MB
    float* h1seq = xp1 + (size_t)T_STEPS * G1_;          // [1024][128] = 512 KB
    float* h2seq = h1seq + (size_t)T_STEPS * H1_;        // [1024][64]  = 256 KB
    u4*    wpk1  = (u4*)(h2seq + (size_t)T_STEPS * H2_); // 8192*16B = 128 KB
    u4*    wpk2  = wpk1 + 8192;                          // 2048*16B =  32 KB
    float* xp2   = xp1;                                  // overlay (xp1 dead after B1)

    hipLaunchKernelGGL(xproj_kernel, dim3(T_STEPS), dim3(G1_), 0, stream,
                       x, W_ih0, b_ih0, b_hh0, xp1);
    hipLaunchKernelGGL(pack_kernel, dim3(40), dim3(256), 0, stream,
                       W_hh0, W_hh1, wpk1, wpk2);
    hipLaunchKernelGGL(lstm1_kernel, dim3(1), dim3(256), 0, stream,
                       xp1, wpk1, h1seq);
    hipLaunchKernelGGL(xproj2_kernel, dim3(T_STEPS), dim3(G2_), 0, stream,
                       h1seq, W_ih1, b_ih1, b_hh1, xp2);
    hipLaunchKernelGGL(lstm2_kernel, dim3(1), dim3(256), 0, stream,
                       xp2, wpk2, h2seq);
    hipLaunchKernelGGL(head_kernel, dim3((T_STEPS * OUT_F + 255) / 256), dim3(256),
                       0, stream, h2seq, W_d, b_d, out);
}